// Round 12
// baseline (428.656 us; speedup 1.0000x reference)
//
#include <hip/hip_runtime.h>
#include <math.h>

#define NN 100000
#define EE 800000
#define ET (EE + NN)
#define BS 256
#define BKTS 391        // cdiv(NN, 256) coarse buckets (dst >> 8)
#define FB_EPB 4096     // edges per block in hist/fill passes
#define LDSCAP 4096     // max edges per bucket (mean 2303, sigma ~45)
#define DBINS 64        // degree bins for balance sort (deg clamped to 63)

typedef _Float16 f16;
typedef __attribute__((ext_vector_type(4))) _Float16 half4;
typedef __attribute__((ext_vector_type(8))) _Float16 half8;
typedef __attribute__((ext_vector_type(4))) float f32x4;
template<int V> struct HV;
template<> struct HV<4>{ typedef half4 type; };
template<> struct HV<8>{ typedef half8 type; };

static inline int cdiv(long a, int b){ return (int)((a + b - 1) / b); }

// ---------------- prep helpers ----------------
template<int K, int M, int KP, int MP, int HH, int CC>
__device__ __forceinline__ void prep_one(int idx, const float* __restrict__ W,
        const float* __restrict__ b, const float* __restrict__ as_,
        const float* __restrict__ ad_, f16* __restrict__ Wpk,
        float* __restrict__ bp, float* __restrict__ Was, float* __restrict__ Wad){
    constexpr int NT = MP / 16;
    if (idx < KP * MP){
        int j    = idx & 7;
        int lane = (idx >> 3) & 63;
        int rest = idx >> 9;
        int nt   = rest % NT;
        int ks   = rest / NT;
        int k = ks * 32 + ((lane >> 4) & 3) * 8 + j;
        int n = nt * 16 + (lane & 15);
        Wpk[idx] = (k < K && n < M) ? (f16)W[k * M + n] : (f16)0.f;
    }
    if (idx < MP) bp[idx] = (idx < M) ? b[idx] : 0.f;
    if (idx < K * HH){
        int k = idx / HH, hd = idx - k * HH;
        float s = 0.f, d = 0.f;
        #pragma unroll
        for (int c = 0; c < CC; c++){
            float w = W[k * M + hd * CC + c];
            s = fmaf(w, as_[hd * CC + c], s);
            d = fmaf(w, ad_[hd * CC + c], d);
        }
        Was[idx] = s;
        Wad[idx] = d;
    }
}

__device__ __forceinline__ void prep_w0(int idx, const float* __restrict__ W0,
                                        f16* __restrict__ Wpk0){
    int j    = idx & 7;
    int lane = (idx >> 3) & 63;
    int nt   = (idx >> 9) & 1;
    int hd   = idx >> 10;
    int k    = ((lane >> 4) & 3) * 8 + j;
    int cih  = nt * 16 + (lane & 15);
    Wpk0[idx] = (cih < 24) ? (f16)W0[k * 240 + hd * 24 + cih] : (f16)0.f;
}

struct PrepAll {
    const float *W[5], *b[5], *as[5], *ad[5];
    f16*   Wpk[5];
    f16*   Wpk0;
    float* bp[5];
    float* Was[5];
    float* Wad[5];
};

// ---------------- K1: prep (blocks 0..239) || edge bucket hist (blocks 240..459) ----
// bucketCount/dcnt zeroed by a single hipMemsetAsync BEFORE this kernel (stream order).
__global__ __launch_bounds__(256) void k_prep_bhist(PrepAll a, const int* __restrict__ ei,
                                                    int* __restrict__ bucketCount){
    if (blockIdx.x < 240){
        int idx = blockIdx.x * 256 + threadIdx.x;
        if (idx < 7680)
            prep_one< 32, 240,  32, 240, 10, 24>(idx,         a.W[0], a.b[0], a.as[0], a.ad[0], a.Wpk[0], a.bp[0], a.Was[0], a.Wad[0]);
        else if (idx < 40448)
            prep_one<240, 120, 256, 128,  5, 24>(idx - 7680,  a.W[1], a.b[1], a.as[1], a.ad[1], a.Wpk[1], a.bp[1], a.Was[1], a.Wad[1]);
        else if (idx < 48640)
            prep_one<120,  48, 128,  64,  2, 24>(idx - 40448, a.W[2], a.b[2], a.as[2], a.ad[2], a.Wpk[2], a.bp[2], a.Was[2], a.Wad[2]);
        else if (idx < 50688)
            prep_one< 48,  24,  64,  32,  1, 24>(idx - 48640, a.W[3], a.b[3], a.as[3], a.ad[3], a.Wpk[3], a.bp[3], a.Was[3], a.Wad[3]);
        else if (idx < 51200)
            prep_one< 24,  12,  32,  16,  1, 12>(idx - 50688, a.W[4], a.b[4], a.as[4], a.ad[4], a.Wpk[4], a.bp[4], a.Was[4], a.Wad[4]);
        else
            prep_w0(idx - 51200, a.W[0], a.Wpk0);
        return;
    }
    // ---- bhist part ----
    __shared__ int hist[BKTS];
    for (int t = threadIdx.x; t < BKTS; t += 256) hist[t] = 0;
    __syncthreads();
    const int e0 = (blockIdx.x - 240) * FB_EPB + threadIdx.x;
    #pragma unroll
    for (int i = 0; i < 16; i++){
        int e = e0 + i * 256;
        if (e < ET){
            int d = (e < EE) ? ei[EE + e] : (e - EE);
            atomicAdd(&hist[d >> 8], 1);
        }
    }
    __syncthreads();
    for (int t = threadIdx.x; t < BKTS; t += 256){
        int c = hist[t];
        if (c) atomicAdd(&bucketCount[t], c);
    }
}

__global__ void k_bscan(const int* __restrict__ bucketCount, int* __restrict__ bucketBase,
                        int* __restrict__ bucketCursor, int* __restrict__ rowptr){
    __shared__ int sh[512];
    int t = threadIdx.x;
    int c = (t < BKTS) ? bucketCount[t] : 0;
    sh[t] = c;
    __syncthreads();
    for (int o = 1; o < 512; o <<= 1){
        int v = (t >= o) ? sh[t - o] : 0;
        __syncthreads();
        sh[t] += v;
        __syncthreads();
    }
    if (t < BKTS){
        int excl = sh[t] - c;
        bucketBase[t] = excl;
        bucketCursor[t] = excl;
    }
    if (t == 0){
        bucketBase[BKTS] = ET;
        rowptr[NN] = ET;
    }
}

// ---------------- K3: bfill (blocks 0..219) || L0 cvt+alpha (blocks 220..610) ----
__global__ __launch_bounds__(256) void k_bfill_cvt(const int* __restrict__ ei,
        int* __restrict__ bucketCursor, unsigned* __restrict__ bpack,
        const float* __restrict__ X, f16* __restrict__ Xh,
        const float* __restrict__ Was, const float* __restrict__ Wad,
        float* __restrict__ als, float* __restrict__ ald){
    __shared__ int hist[BKTS];
    __shared__ int base[BKTS];
    if (blockIdx.x < 220){
        for (int t = threadIdx.x; t < BKTS; t += 256) hist[t] = 0;
        __syncthreads();
        const int e0 = blockIdx.x * FB_EPB + threadIdx.x;
        unsigned pk[16], rb[16];
        #pragma unroll
        for (int i = 0; i < 16; i++){
            int e = e0 + i * 256;
            rb[i] = 0xFFFFFFFFu;
            if (e < ET){
                int s, d;
                if (e < EE){ s = ei[e]; d = ei[EE + e]; } else { s = e - EE; d = s; }
                int b = d >> 8;
                int r = atomicAdd(&hist[b], 1);
                pk[i] = ((unsigned)(d & 255) << 17) | (unsigned)s;
                rb[i] = ((unsigned)r << 9) | (unsigned)b;
            }
        }
        __syncthreads();
        for (int t = threadIdx.x; t < BKTS; t += 256){
            int c = hist[t];
            base[t] = c ? atomicAdd(&bucketCursor[t], c) : 0;
        }
        __syncthreads();
        #pragma unroll
        for (int i = 0; i < 16; i++){
            if (rb[i] != 0xFFFFFFFFu){
                int b = rb[i] & 511;
                int r = rb[i] >> 9;
                bpack[base[b] + r] = pk[i];
            }
        }
        return;
    }
    // ---- L0 cvt+alpha part (stride-12 als/ald rows) ----
    int n = (blockIdx.x - 220) * 256 + threadIdx.x;
    if (n >= NN) return;
    float xr[32];
    #pragma unroll
    for (int i = 0; i < 8; i++){
        float4 v = *(const float4*)(X + (long)n * 32 + i * 4);
        xr[i * 4 + 0] = v.x; xr[i * 4 + 1] = v.y;
        xr[i * 4 + 2] = v.z; xr[i * 4 + 3] = v.w;
    }
    #pragma unroll
    for (int i = 0; i < 4; i++){
        half8 h;
        #pragma unroll
        for (int c = 0; c < 8; c++) h[c] = (f16)xr[i * 8 + c];
        *(half8*)(Xh + (long)n * 32 + i * 8) = h;
    }
    float s[10] = {}, d[10] = {};
    for (int k = 0; k < 32; k++){
        float x = xr[k];
        #pragma unroll
        for (int hd = 0; hd < 10; hd++){
            s[hd] = fmaf(x, Was[k * 10 + hd], s[hd]);
            d[hd] = fmaf(x, Wad[k * 10 + hd], d[hd]);
        }
    }
    #pragma unroll
    for (int hd = 0; hd < 10; hd++){
        als[(long)n * 12 + hd] = s[hd];
        ald[(long)n * 12 + hd] = d[hd];
    }
}

// Pass 4: block per bucket: LDS counting-sort by dstlow; coalesced rowptr+ssrc.
// Degree histogram folded in, TWO-LEVEL (round-7's per-node global atomic cost +330us).
__global__ __launch_bounds__(256) void k_bsort(const unsigned* __restrict__ bpack,
        const int* __restrict__ bucketBase, int* __restrict__ rowptr,
        int* __restrict__ ssrc, int* __restrict__ dcnt){
    __shared__ int cnt[256];
    __shared__ int off[256];
    __shared__ int dh[DBINS];
    __shared__ unsigned stage[LDSCAP];
    int b = blockIdx.x;
    int n0 = bucketBase[b], n1 = bucketBase[b + 1];
    int nE = n1 - n0;
    int t = threadIdx.x;
    cnt[t] = 0;
    if (t < DBINS) dh[t] = 0;
    __syncthreads();
    for (int i = t; i < nE; i += 256){
        unsigned v = bpack[n0 + i];
        atomicAdd(&cnt[v >> 17], 1);
    }
    __syncthreads();
    int cv = cnt[t];
    off[t] = cv;
    __syncthreads();
    for (int o = 1; o < 256; o <<= 1){
        int v = (t >= o) ? off[t - o] : 0;
        __syncthreads();
        off[t] += v;
        __syncthreads();
    }
    int excl = off[t] - cv;
    __syncthreads();
    off[t] = excl;
    cnt[t] = 0;
    __syncthreads();
    for (int i = t; i < nE; i += 256){
        unsigned v = bpack[n0 + i];
        int dl = v >> 17;
        int r = atomicAdd(&cnt[dl], 1);
        stage[off[dl] + r] = v;
    }
    int d = b * 256 + t;
    if (d < NN){
        rowptr[d] = n0 + excl;
        int dg = (cv > DBINS - 1) ? (DBINS - 1) : cv;
        atomicAdd(&dh[dg], 1);          // LDS atomic (cheap)
    }
    __syncthreads();
    for (int i = t; i < nE; i += 256){
        unsigned v = stage[i];
        ssrc[n0 + i] = (int)(v & 0x1FFFFu);
    }
    if (t < DBINS && dh[t]) atomicAdd(&dcnt[t], dh[t]);  // 64 global atomics/block
}

// ---------------- online-softmax update (proven since round 2) ----------------
__device__ __forceinline__ void smx_upd(float& ma, float& L, float& z, float e, float adv){
    float mn = fmaxf(ma, e);
    float Ln = mn + adv; Ln = (Ln >= 0.f) ? Ln : 0.2f * Ln;
    float ev = e + adv;  ev = (ev >= 0.f) ? ev : 0.2f * ev;
    z = z * __expf(L - Ln) + __expf(ev - Ln);
    ma = mn; L = Ln;
}

// ---------------- K5: L0 mzatt (blocks 1..) || degree LPT scan (block 0) ----------
// mzatt: per-(node, head-pair) online softmax -> f16 att (aggX0 consumes it).
template<int HH, int SL, int ATTS, int TPN>
__global__ __launch_bounds__(256) void k_mzatt_dscan(const float* __restrict__ als,
        const float* __restrict__ ald, const int* __restrict__ rowptr,
        const int* __restrict__ ssrc, f16* __restrict__ att,
        const int* __restrict__ dcnt, int* __restrict__ dcur){
    constexpr int HPT = HH / TPN;
    if (blockIdx.x == 0){
        // descending-degree exclusive prefix (bin 63 first -> LPT order)
        __shared__ int sh[DBINS];
        int t = threadIdx.x;
        if (t < DBINS){
            sh[t] = dcnt[t];
        }
        __syncthreads();
        if (t < DBINS){
            int off = 0;
            for (int b = t + 1; b < DBINS; ++b) off += sh[b];
            dcur[t] = off;
        }
        return;
    }
    long idx = (long)(blockIdx.x - 1) * 256 + threadIdx.x;
    if (idx >= (long)NN * TPN) return;
    int n = (int)(idx / TPN);
    int g = (int)(idx - (long)n * TPN);
    const int c0 = g * HPT;
    float adv[HPT], ma[HPT], L[HPT], z[HPT];
    #pragma unroll
    for (int h = 0; h < HPT; h++){
        adv[h] = ald[(long)n * SL + c0 + h];
        ma[h] = -1e30f; L[h] = -1e30f; z[h] = 0.f;
    }
    const int beg = rowptr[n], end = rowptr[n + 1];
    int p = beg;
    for (; p + 4 <= end; p += 4){
        int s0 = ssrc[p], s1 = ssrc[p+1], s2 = ssrc[p+2], s3 = ssrc[p+3];
        float e0[HPT], e1[HPT], e2[HPT], e3[HPT];
        if constexpr (HPT == 2){
            float2 v0 = *(const float2*)(als + (long)s0 * SL + c0);
            float2 v1 = *(const float2*)(als + (long)s1 * SL + c0);
            float2 v2 = *(const float2*)(als + (long)s2 * SL + c0);
            float2 v3 = *(const float2*)(als + (long)s3 * SL + c0);
            e0[0]=v0.x; e0[1]=v0.y; e1[0]=v1.x; e1[1]=v1.y;
            e2[0]=v2.x; e2[1]=v2.y; e3[0]=v3.x; e3[1]=v3.y;
        } else {
            e0[0] = als[(long)s0 * SL + c0];
            e1[0] = als[(long)s1 * SL + c0];
            e2[0] = als[(long)s2 * SL + c0];
            e3[0] = als[(long)s3 * SL + c0];
        }
        #pragma unroll
        for (int h = 0; h < HPT; h++){
            smx_upd(ma[h], L[h], z[h], e0[h], adv[h]);
            smx_upd(ma[h], L[h], z[h], e1[h], adv[h]);
            smx_upd(ma[h], L[h], z[h], e2[h], adv[h]);
            smx_upd(ma[h], L[h], z[h], e3[h], adv[h]);
        }
    }
    for (; p < end; ++p){
        int s = ssrc[p];
        float e[HPT];
        if constexpr (HPT == 2){
            float2 v = *(const float2*)(als + (long)s * SL + c0);
            e[0] = v.x; e[1] = v.y;
        } else {
            e[0] = als[(long)s * SL + c0];
        }
        #pragma unroll
        for (int h = 0; h < HPT; h++) smx_upd(ma[h], L[h], z[h], e[h], adv[h]);
    }
    float zi[HPT];
    int pos[HPT];
    #pragma unroll
    for (int h = 0; h < HPT; h++){
        zi[h] = 1.f / z[h];
        int hh = c0 + h;
        pos[h] = (ATTS == 16) ? (hh + ((hh >= 5) ? 3 : 0)) : hh;
    }
    for (p = beg; p < end; ++p){
        int s = ssrc[p];
        float e[HPT];
        if constexpr (HPT == 2){
            float2 v = *(const float2*)(als + (long)s * SL + c0);
            e[0] = v.x; e[1] = v.y;
        } else {
            e[0] = als[(long)s * SL + c0];
        }
        #pragma unroll
        for (int h = 0; h < HPT; h++){
            float ev = e[h] + adv[h]; ev = (ev >= 0.f) ? ev : 0.2f * ev;
            att[(long)p * ATTS + pos[h]] = (f16)(__expf(ev - L[h]) * zi[h]);
        }
    }
}

__global__ __launch_bounds__(256) void k_dfill(const int* __restrict__ rowptr,
        int* __restrict__ dcur, int* __restrict__ perm){
    __shared__ int h[DBINS];
    __shared__ int base[DBINS];
    int t = threadIdx.x;
    if (t < DBINS) h[t] = 0;
    __syncthreads();
    int n = blockIdx.x * 256 + t;
    int d = 0, r = 0;
    if (n < NN){
        d = rowptr[n + 1] - rowptr[n];
        if (d > DBINS - 1) d = DBINS - 1;
        r = atomicAdd(&h[d], 1);
    }
    __syncthreads();
    if (t < DBINS){
        int c = h[t];
        base[t] = c ? atomicAdd(&dcur[t], c) : 0;
    }
    __syncthreads();
    if (n < NN) perm[base[d] + r] = n;
}

// ---------------- L0 FUSED: aggregate X per head + block-diag MFMA GEMM + relu ----
// Nodes via degree-balanced perm (barrier waits on ~mean, not max-of-32; measured -4.4us).
__global__ __launch_bounds__(256) void k_aggX0_gemm(const f16* __restrict__ Xh,
        const f16* __restrict__ att, const int* __restrict__ rowptr,
        const int* __restrict__ ssrc, const int* __restrict__ perm,
        const f16* __restrict__ Wpk0, const float* __restrict__ bp0,
        f16* __restrict__ X1){
    constexpr int SA = 328;   // Xagg tile stride (f16)
    constexpr int SO = 264;   // X1 tile stride (f16)
    __shared__ f16 smem[32 * SA];     // 20992 B; X1 tile aliases (after barrier)
    const int t = threadIdx.x;
    const int n0 = blockIdx.x * 32;

    {   // ---- phase 1: aggregation, 4-edge unroll for MLP ----
        const int nloc = t >> 3;
        const int hg   = (t >> 2) & 1;
        const int ch   = t & 3;
        const int n    = perm[n0 + nloc];
        float acc[5][8] = {};
        int beg = rowptr[n], end = rowptr[n + 1];
        int p = beg;
        for (; p + 4 <= end; p += 4){
            int s0 = ssrc[p], s1 = ssrc[p+1], s2 = ssrc[p+2], s3 = ssrc[p+3];
            half8 x0 = *(const half8*)(Xh + (long)s0 * 32 + ch * 8);
            half8 x1 = *(const half8*)(Xh + (long)s1 * 32 + ch * 8);
            half8 x2 = *(const half8*)(Xh + (long)s2 * 32 + ch * 8);
            half8 x3 = *(const half8*)(Xh + (long)s3 * 32 + ch * 8);
            half8 a0 = *(const half8*)(att + (long)p * 16 + hg * 8);
            half8 a1 = *(const half8*)(att + (long)(p+1) * 16 + hg * 8);
            half8 a2 = *(const half8*)(att + (long)(p+2) * 16 + hg * 8);
            half8 a3 = *(const half8*)(att + (long)(p+3) * 16 + hg * 8);
            #pragma unroll
            for (int h = 0; h < 5; h++){
                float w0 = (float)a0[h], w1 = (float)a1[h];
                float w2 = (float)a2[h], w3 = (float)a3[h];
                #pragma unroll
                for (int c = 0; c < 8; c++){
                    acc[h][c] = fmaf(w0, (float)x0[c], acc[h][c]);
                    acc[h][c] = fmaf(w1, (float)x1[c], acc[h][c]);
                    acc[h][c] = fmaf(w2, (float)x2[c], acc[h][c]);
                    acc[h][c] = fmaf(w3, (float)x3[c], acc[h][c]);
                }
            }
        }
        for (; p < end; ++p){
            int s = ssrc[p];
            half8 xv = *(const half8*)(Xh + (long)s * 32 + ch * 8);
            half8 av = *(const half8*)(att + (long)p * 16 + hg * 8);
            #pragma unroll
            for (int h = 0; h < 5; h++){
                float w = (float)av[h];
                #pragma unroll
                for (int c = 0; c < 8; c++)
                    acc[h][c] = fmaf(w, (float)xv[c], acc[h][c]);
            }
        }
        #pragma unroll
        for (int h = 0; h < 5; h++){
            half8 o;
            #pragma unroll
            for (int c = 0; c < 8; c++) o[c] = (f16)acc[h][c];
            *(half8*)(smem + nloc * SA + (hg * 5 + h) * 32 + ch * 8) = o;
        }
    }
    __syncthreads();

    // ---- phase 2: prefetch A-frags, then MFMA + epilogue into LDS X1 tile ----
    const int wave = t >> 6;
    const int lane = t & 63;
    const int quad = lane >> 4;
    const int l16  = lane & 15;
    const int mt   = wave & 1;
    half8 afr[5];
    #pragma unroll
    for (int i = 0; i < 5; i++){
        const int hd = (wave + 4 * i) >> 1;
        afr[i] = *(const half8*)(smem + (mt * 16 + l16) * SA + hd * 32 + quad * 8);
    }
    __syncthreads();                    // all Xagg reads done before overwrite
    #pragma unroll
    for (int i = 0; i < 5; i++){
        const int hd = (wave + 4 * i) >> 1;
        #pragma unroll
        for (int nt = 0; nt < 2; nt++){
            half8 bfr = *(const half8*)(Wpk0 + ((hd * 2 + nt) * 64 + lane) * 8);
            f32x4 acc2 = (f32x4){0.f, 0.f, 0.f, 0.f};
            acc2 = __builtin_amdgcn_mfma_f32_16x16x32_f16(afr[i], bfr, acc2, 0, 0, 0);
            int cih = nt * 16 + l16;
            if (cih < 24){
                float bv = bp0[hd * 24 + cih];
                #pragma unroll
                for (int reg = 0; reg < 4; reg++){
                    int rl = mt * 16 + quad * 4 + reg;
                    float v = acc2[reg] + bv;
                    smem[rl * SO + hd * 24 + cih] = (f16)((v > 0.f) ? v : 0.f);
                }
            }
        }
    }
    __syncthreads();

    // ---- phase 3: coalesced X1 stores (rows scattered via perm, 512B each) ----
    const half8 hz = {};
    #pragma unroll
    for (int c = t; c < 1024; c += 256){
        int row = c >> 5, c8 = c & 31;
        long rn = perm[n0 + row];
        half8 v = (c8 >= 30) ? hz : *(const half8*)(smem + row * SO + c8 * 8);
        *(half8*)(X1 + rn * 256 + c8 * 8) = v;
    }
}

// ---------------- MFMA GEMM + fused alpha (layers 1..4) ----------------
// GEMM writes the 128-row H tile to global AND to LDS; after a barrier the block
// computes als/ald from the LDS tile (saves the alpha dispatch + H2 re-read).
template<int KP, int MPH, int M, int HH, int CC, int SL>
__global__ __launch_bounds__(256) void k_gemm_alpha(const f16* __restrict__ Xh,
        const f16* __restrict__ Wpk, const float* __restrict__ as_,
        const float* __restrict__ ad_, f16* __restrict__ H2,
        float* __restrict__ als, float* __restrict__ ald){
    constexpr int NT = MPH / 16;
    constexpr int KS = KP / 32;
    __shared__ f16 hs[128 * MPH];      // 32KB @ MPH=128
    const int wave = threadIdx.x >> 6;
    const int lane = threadIdx.x & 63;
    const int quad = lane >> 4;
    const int l16  = lane & 15;
    const long row0 = (long)blockIdx.x * 128 + wave * 32;

    f32x4 acc[2][NT];
    #pragma unroll
    for (int mt = 0; mt < 2; mt++)
        #pragma unroll
        for (int nt = 0; nt < NT; nt++)
            acc[mt][nt] = (f32x4){0.f, 0.f, 0.f, 0.f};

    const long r0 = row0 + l16;
    const long r1 = row0 + 16 + l16;
    const half8 hz = {};
    half8 a0 = (r0 < NN) ? *(const half8*)(Xh + r0 * KP + quad * 8) : hz;
    half8 a1 = (r1 < NN) ? *(const half8*)(Xh + r1 * KP + quad * 8) : hz;
    half8 bc[NT];
    #pragma unroll
    for (int nt = 0; nt < NT; nt++)
        bc[nt] = *(const half8*)(Wpk + ((long)nt * 64 + lane) * 8);

    for (int ks = 0; ks < KS; ks++){
        half8 n0 = hz, n1 = hz, bn[NT];
        if (ks + 1 < KS){
            const int kk = (ks + 1) * 32 + quad * 8;
            n0 = (r0 < NN) ? *(const half8*)(Xh + r0 * KP + kk) : hz;
            n1 = (r1 < NN) ? *(const half8*)(Xh + r1 * KP + kk) : hz;
            const f16* bp_ = Wpk + ((long)(ks + 1) * NT * 64 + lane) * 8;
            #pragma unroll
            for (int nt = 0; nt < NT; nt++)
                bn[nt] = *(const half8*)(bp_ + (long)nt * 512);
        } else {
            #pragma unroll
            for (int nt = 0; nt < NT; nt++) bn[nt] = hz;
        }
        #pragma unroll
        for (int nt = 0; nt < NT; nt++){
            acc[0][nt] = __builtin_amdgcn_mfma_f32_16x16x32_f16(a0, bc[nt], acc[0][nt], 0, 0, 0);
            acc[1][nt] = __builtin_amdgcn_mfma_f32_16x16x32_f16(a1, bc[nt], acc[1][nt], 0, 0, 0);
        }
        a0 = n0; a1 = n1;
        #pragma unroll
        for (int nt = 0; nt < NT; nt++) bc[nt] = bn[nt];
    }
    #pragma unroll
    for (int mt = 0; mt < 2; mt++){
        #pragma unroll
        for (int reg = 0; reg < 4; reg++){
            const int rl = wave * 32 + mt * 16 + quad * 4 + reg;
            long r = row0 + mt * 16 + quad * 4 + reg;
            #pragma unroll
            for (int nt = 0; nt < NT; nt++)
                hs[rl * MPH + nt * 16 + l16] = (f16)acc[mt][nt][reg];
            if (r < NN){
                #pragma unroll
                for (int nt = 0; nt < NT; nt++)
                    H2[r * MPH + nt * 16 + l16] = (f16)acc[mt][nt][reg];
            }
        }
    }
    __syncthreads();

    // ---- fused alpha: per (row, head) dot with as/ad from the LDS tile ----
    const long nb = (long)blockIdx.x * 128;
    for (int tk = threadIdx.x; tk < 128 * HH; tk += 256){
        int row = tk / HH, hd = tk - row * HH;
        long n = nb + row;
        if (n < NN){
            const f16* hrow = hs + row * MPH + hd * CC;
            float s = 0.f, d = 0.f;
            #pragma unroll
            for (int c0 = 0; c0 < CC; c0 += 4){
                half4 hv = *(const half4*)(hrow + c0);
                #pragma unroll
                for (int j = 0; j < 4; j++){
                    float w = (float)hv[j];
                    s = fmaf(w, as_[hd * CC + c0 + j], s);
                    d = fmaf(w, ad_[hd * CC + c0 + j], d);
                }
            }
            als[n * SL + hd] = s;
            ald[n * SL + hd] = d;
        }
    }
}

// ---------------- col-chunk fused softmax+aggregate (layers 1..4) ----------------
// Pass A (online softmax) computed ONCE per head by lanes q<HH, then (L, 1/z)
// wave-shuffled to all TPN lanes of the node (bit-exact vs redundant compute;
// cuts pass-A VALU issue ~TPN/HH x). TPN in {16,8,4} divides 64; node lane-groups
// are wave-aligned; shuffle source lanes never early-return.
template<int HH, int CC, int MPH, int MPO, int VEC, bool O16, int SL>
__global__ __launch_bounds__(256) void k_aggsm_h(const f16* __restrict__ H2,
        const float* __restrict__ als, const float* __restrict__ ald,
        const int* __restrict__ rowptr, const int* __restrict__ ssrc,
        const float* __restrict__ bp, f16* __restrict__ out16,
        float* __restrict__ out32, int MREAL){
    constexpr int TPN = MPO / VEC;
    typedef typename HV<VEC>::type hvec;
    long idx = (long)blockIdx.x * 256 + threadIdx.x;
    if (idx >= (long)NN * TPN) return;
    const int lane = threadIdx.x & 63;
    int n = (int)(idx / TPN);
    int q = (int)(idx - (long)n * TPN);
    int j0 = q * VEC;
    int hd = j0 / CC; if (hd > HH - 1) hd = HH - 1;
    const int beg = rowptr[n], end = rowptr[n + 1];

    // ---- pass A: lanes q<HH compute head q's (m, L, z); others idle ----
    float myL = 0.f, myzi = 0.f;
    if (q < HH){
        const float advq = ald[(long)n * SL + q];
        float ma = -1e30f, L = -1e30f, z = 0.f;
        int p = beg;
        for (; p + 4 <= end; p += 4){
            int s0 = ssrc[p], s1 = ssrc[p+1], s2 = ssrc[p+2], s3 = ssrc[p+3];
            float e0 = als[(long)s0 * SL + q];
            float e1 = als[(long)s1 * SL + q];
            float e2 = als[(long)s2 * SL + q];
            float e3 = als[(long)s3 * SL + q];
            smx_upd(ma, L, z, e0, advq);
            smx_upd(ma, L, z, e1, advq);
            smx_upd(ma, L, z, e2, advq);
            smx_upd(ma, L, z, e3, advq);
        }
        for (; p < end; ++p)
            smx_upd(ma, L, z, als[(long)ssrc[p] * SL + q], advq);
        myL = L; myzi = 1.f / z;
    }
    const int srcLane = (lane & ~(TPN - 1)) | hd;
    const float L  = __shfl(myL,  srcLane, 64);
    const float zi = __shfl(myzi, srcLane, 64);
    if constexpr (!O16){ if (j0 >= MREAL) return; }
    const float adv = ald[(long)n * SL + hd];

    // ---- pass B: weighted gather (als rows cache-hot) ----
    float acc[VEC] = {};
    int p = beg;
    for (; p + 4 <= end; p += 4){
        int s0 = ssrc[p], s1 = ssrc[p+1], s2 = ssrc[p+2], s3 = ssrc[p+3];
        float e0 = als[(long)s0 * SL + hd];
        float e1 = als[(long)s1 * SL + hd];
        float e2 = als[(long)s2 * SL + hd];
        float e3 = als[(long)s3 * SL + hd];
        e0 += adv; e0 = (e0 >= 0.f) ? e0 : 0.2f * e0;
        e1 += adv; e1 = (e1 >= 0.f) ? e1 : 0.2f * e1;
        e2 += adv; e2 = (e2 >= 0.f) ? e2 : 0.2f * e2;
        e3 += adv; e3 = (e3 >= 0.f) ? e3 : 0.2f * e3;
        float w0 = __expf(e0 - L) * zi;
        float w1 = __expf(e1 - L) * zi;
        float w2 = __expf(e2 - L) * zi;
        float w3 = __expf(e3 - L) * zi;
        hvec h0 = *(const hvec*)(H2 + (long)s0 * MPH + j0);
        hvec h1 = *(const hvec*)(H2 + (long)s1 * MPH + j0);
        hvec h2 = *(const hvec*)(H2 + (long)s2 * MPH + j0);
        hvec h3 = *(const hvec*)(H2 + (long)s3 * MPH + j0);
        #pragma unroll
        for (int c = 0; c < VEC; c++){
            acc[c] = fmaf(w0, (float)h0[c], acc[c]);
            acc[c] = fmaf(w1, (float)h1[c], acc[c]);
            acc[c] = fmaf(w2, (float)h2[c], acc[c]);
            acc[c] = fmaf(w3, (float)h3[c], acc[c]);
        }
    }
    for (; p < end; ++p){
        int s = ssrc[p];
        float e = als[(long)s * SL + hd] + adv;
        e = (e >= 0.f) ? e : 0.2f * e;
        float w = __expf(e - L) * zi;
        hvec hv = *(const hvec*)(H2 + (long)s * MPH + j0);
        #pragma unroll
        for (int c = 0; c < VEC; c++)
            acc[c] = fmaf(w, (float)hv[c], acc[c]);
    }
    if constexpr (O16){
        hvec o;
        #pragma unroll
        for (int c = 0; c < VEC; c++){
            float v = acc[c] + bp[j0 + c];
            o[c] = (f16)((v > 0.f) ? v : 0.f);
        }
        *(hvec*)(out16 + (long)n * MPO + j0) = o;
    } else {
        #pragma unroll
        for (int c = 0; c < VEC; c++){
            float v = acc[c] + bp[j0 + c];
            out32[(long)n * MREAL + j0 + c] = (v > 0.f) ? v : 0.f;
        }
    }
}

// ---------------- layer driver (layers 1..4): 2 dispatches/layer ----------------
template<int K, int M, int KP, int MPH, int MPO, int HH, int CC, int VEC, bool O16, int SL>
static void run_layer(const f16* Xin, f16* H2,
                      const f16* Wpk, const float* bp,
                      const float* asv, const float* adv,
                      float* als, float* ald,
                      const int* rowptr, const int* ssrc,
                      f16* Xnext, float* out32, hipStream_t stream){
    constexpr int OTPN = MPO / VEC;
    k_gemm_alpha<KP, MPH, M, HH, CC, SL><<<cdiv(NN, 128), 256, 0, stream>>>(
        Xin, Wpk, asv, adv, H2, als, ald);
    k_aggsm_h<HH, CC, MPH, MPO, VEC, O16, SL><<<cdiv((long)NN * OTPN, 256), 256, 0, stream>>>(
        H2, als, ald, rowptr, ssrc, bp, Xnext, out32, M);
}

extern "C" void kernel_launch(void* const* d_in, const int* in_sizes, int n_in,
                              void* d_out, int out_size, void* d_ws, size_t ws_size,
                              hipStream_t stream){
    const float* x0 = (const float*)d_in[0];
    const int*   ei = (const int*)d_in[1];
    PrepAll pa;
    for (int i = 0; i < 5; i++){
        pa.W[i]  = (const float*)d_in[3 + 4 * i];
        pa.b[i]  = (const float*)d_in[4 + 4 * i];
        pa.as[i] = (const float*)d_in[5 + 4 * i];
        pa.ad[i] = (const float*)d_in[6 + 4 * i];
    }

    char* p = (char*)d_ws;
    auto alloc = [&](size_t bytes) -> char* {
        char* r = p;
        p += (bytes + 255) & ~(size_t)255;
        return r;
    };
    f16*   Xh     = (f16*)alloc((size_t)NN * 256 * 2);   // X0h (stride 32), then hidden H (layers 1..4)
    f16*   H2     = (f16*)alloc((size_t)NN * 320 * 2);   // X1 (stride 256), then X2/X3/X4 activations
    f16*   att    = (f16*)alloc((size_t)ET * 16 * 2);    // L0 only
    float* als    = (float*)alloc((size_t)NN * 12 * 4);  // padded rows (stride 12/8/2/1/1)
    float* ald    = (float*)alloc((size_t)NN * 12 * 4);
    const int wpkSz[5] = {7680, 32768, 8192, 2048, 512};
    const int mpSz[5]  = {240, 128, 64, 32, 16};
    const int khSz[5]  = {320, 1200, 240, 48, 24};
    for (int i = 0; i < 5; i++){
        pa.Wpk[i] = (f16*)alloc((size_t)wpkSz[i] * 2);
        pa.bp[i]  = (float*)alloc((size_t)mpSz[i] * 4);
        pa.Was[i] = (float*)alloc((size_t)khSz[i] * 4);
        pa.Wad[i] = (float*)alloc((size_t)khSz[i] * 4);
    }
    pa.Wpk0 = (f16*)alloc((size_t)10240 * 2);
    int*      cntbuf       = (int*)alloc((size_t)(BKTS + DBINS) * 4);
    int*      bucketCount  = cntbuf;            // zeroed by one memset
    int*      dcnt         = cntbuf + BKTS;
    int*      bucketBase   = (int*)alloc((size_t)(BKTS + 1) * 4);
    int*      bucketCursor = (int*)alloc((size_t)BKTS * 4);
    unsigned* bpack        = (unsigned*)alloc((size_t)ET * 4);
    int*      rowptr       = (int*)alloc((size_t)(NN + 1) * 4);
    int*      ssrc         = (int*)alloc((size_t)ET * 4);
    int*      dcur         = (int*)alloc((size_t)DBINS * 4);
    int*      perm         = (int*)alloc((size_t)NN * 4);

    // ---- zero counters (stream-ordered, graph-capture safe) ----
    hipMemsetAsync(cntbuf, 0, (size_t)(BKTS + DBINS) * 4, stream);

    // ---- K1: prep || bhist;  K2: bscan;  K3: bfill || L0 cvt+alpha;
    //      K4: bsort (+deg hist);  K5: L0 mzatt || dscan;  K6: dfill ----
    k_prep_bhist<<<240 + cdiv(ET, FB_EPB), 256, 0, stream>>>(pa, ei, bucketCount);
    k_bscan<<<1, 512, 0, stream>>>(bucketCount, bucketBase, bucketCursor, rowptr);
    k_bfill_cvt<<<cdiv(ET, FB_EPB) + cdiv(NN, 256), 256, 0, stream>>>(
        ei, bucketCursor, bpack, x0, Xh, pa.Was[0], pa.Wad[0], als, ald);
    k_bsort<<<BKTS, 256, 0, stream>>>(bpack, bucketBase, rowptr, ssrc, dcnt);
    k_mzatt_dscan<10, 12, 16, 5><<<1 + cdiv((long)NN * 5, 256), 256, 0, stream>>>(
        als, ald, rowptr, ssrc, att, dcnt, dcur);
    k_dfill<<<cdiv(NN, 256), 256, 0, stream>>>(rowptr, dcur, perm);

    // ---- L0 fused agg+GEMM (Xagg never hits HBM) ----
    k_aggX0_gemm<<<NN / 32, 256, 0, stream>>>(Xh, att, rowptr, ssrc, perm,
        pa.Wpk0, pa.bp[0], H2 /*X1, stride 256*/);

    // ---- Layers 1..4 (2 dispatches each; alpha fused into GEMM epilogue) ----
    //         K    M   KP  MPH  MPO  HH  CC VEC  O16  SL
    run_layer<240, 120, 256, 128, 128,  5, 24, 8, true,  8>(H2, Xh, pa.Wpk[1],
        pa.bp[1], pa.as[1], pa.ad[1], als, ald, rowptr, ssrc, H2, nullptr, stream);
    run_layer<120,  48, 128,  64,  64,  2, 24, 8, true,  2>(H2, Xh, pa.Wpk[2],
        pa.bp[2], pa.as[2], pa.ad[2], als, ald, rowptr, ssrc, H2, nullptr, stream);
    run_layer< 48,  24,  64,  32,  32,  1, 24, 8, true,  1>(H2, Xh, pa.Wpk[3],
        pa.bp[3], pa.as[3], pa.ad[3], als, ald, rowptr, ssrc, H2, nullptr, stream);
    run_layer< 24,  12,  32,  16,  16,  1, 12, 4, false, 1>(H2, Xh, pa.Wpk[4],
        pa.bp[4], pa.as[4], pa.ad[4], als, ald, rowptr, ssrc, nullptr, (float*)d_out, stream);
}

// Round 13
// 419.168 us; speedup vs baseline: 1.0226x; 1.0226x over previous
//
#include <hip/hip_runtime.h>
#include <math.h>

#define NN 100000
#define EE 800000
#define ET (EE + NN)
#define BS 256
#define BKTS 391        // cdiv(NN, 256) coarse buckets (dst >> 8)
#define FB_EPB 4096     // edges per block in hist/fill passes
#define LDSCAP 4096     // max edges per bucket (mean 2303, sigma ~45)
#define DBINS 64        // degree bins for balance sort (deg clamped to 63)

typedef _Float16 f16;
typedef __attribute__((ext_vector_type(4))) _Float16 half4;
typedef __attribute__((ext_vector_type(8))) _Float16 half8;
typedef __attribute__((ext_vector_type(4))) float f32x4;
template<int V> struct HV;
template<> struct HV<4>{ typedef half4 type; };
template<> struct HV<8>{ typedef half8 type; };

static inline int cdiv(long a, int b){ return (int)((a + b - 1) / b); }

// ---------------- prep helpers ----------------
template<int K, int M, int KP, int MP, int HH, int CC>
__device__ __forceinline__ void prep_one(int idx, const float* __restrict__ W,
        const float* __restrict__ b, const float* __restrict__ as_,
        const float* __restrict__ ad_, f16* __restrict__ Wpk,
        float* __restrict__ bp, float* __restrict__ Was, float* __restrict__ Wad){
    constexpr int NT = MP / 16;
    if (idx < KP * MP){
        int j    = idx & 7;
        int lane = (idx >> 3) & 63;
        int rest = idx >> 9;
        int nt   = rest % NT;
        int ks   = rest / NT;
        int k = ks * 32 + ((lane >> 4) & 3) * 8 + j;
        int n = nt * 16 + (lane & 15);
        Wpk[idx] = (k < K && n < M) ? (f16)W[k * M + n] : (f16)0.f;
    }
    if (idx < MP) bp[idx] = (idx < M) ? b[idx] : 0.f;
    if (idx < K * HH){
        int k = idx / HH, hd = idx - k * HH;
        float s = 0.f, d = 0.f;
        #pragma unroll
        for (int c = 0; c < CC; c++){
            float w = W[k * M + hd * CC + c];
            s = fmaf(w, as_[hd * CC + c], s);
            d = fmaf(w, ad_[hd * CC + c], d);
        }
        Was[idx] = s;
        Wad[idx] = d;
    }
}

__device__ __forceinline__ void prep_w0(int idx, const float* __restrict__ W0,
                                        f16* __restrict__ Wpk0){
    int j    = idx & 7;
    int lane = (idx >> 3) & 63;
    int nt   = (idx >> 9) & 1;
    int hd   = idx >> 10;
    int k    = ((lane >> 4) & 3) * 8 + j;
    int cih  = nt * 16 + (lane & 15);
    Wpk0[idx] = (cih < 24) ? (f16)W0[k * 240 + hd * 24 + cih] : (f16)0.f;
}

struct PrepAll {
    const float *W[5], *b[5], *as[5], *ad[5];
    f16*   Wpk[5];
    f16*   Wpk0;
    float* bp[5];
    float* Was[5];
    float* Wad[5];
};

// ---------------- K1: prep (blocks 0..239) || edge bucket hist (blocks 240..459) ----
// bucketCount/dcnt zeroed by a single hipMemsetAsync BEFORE this kernel (stream order).
__global__ __launch_bounds__(256) void k_prep_bhist(PrepAll a, const int* __restrict__ ei,
                                                    int* __restrict__ bucketCount){
    if (blockIdx.x < 240){
        int idx = blockIdx.x * 256 + threadIdx.x;
        if (idx < 7680)
            prep_one< 32, 240,  32, 240, 10, 24>(idx,         a.W[0], a.b[0], a.as[0], a.ad[0], a.Wpk[0], a.bp[0], a.Was[0], a.Wad[0]);
        else if (idx < 40448)
            prep_one<240, 120, 256, 128,  5, 24>(idx - 7680,  a.W[1], a.b[1], a.as[1], a.ad[1], a.Wpk[1], a.bp[1], a.Was[1], a.Wad[1]);
        else if (idx < 48640)
            prep_one<120,  48, 128,  64,  2, 24>(idx - 40448, a.W[2], a.b[2], a.as[2], a.ad[2], a.Wpk[2], a.bp[2], a.Was[2], a.Wad[2]);
        else if (idx < 50688)
            prep_one< 48,  24,  64,  32,  1, 24>(idx - 48640, a.W[3], a.b[3], a.as[3], a.ad[3], a.Wpk[3], a.bp[3], a.Was[3], a.Wad[3]);
        else if (idx < 51200)
            prep_one< 24,  12,  32,  16,  1, 12>(idx - 50688, a.W[4], a.b[4], a.as[4], a.ad[4], a.Wpk[4], a.bp[4], a.Was[4], a.Wad[4]);
        else
            prep_w0(idx - 51200, a.W[0], a.Wpk0);
        return;
    }
    // ---- bhist part ----
    __shared__ int hist[BKTS];
    for (int t = threadIdx.x; t < BKTS; t += 256) hist[t] = 0;
    __syncthreads();
    const int e0 = (blockIdx.x - 240) * FB_EPB + threadIdx.x;
    #pragma unroll
    for (int i = 0; i < 16; i++){
        int e = e0 + i * 256;
        if (e < ET){
            int d = (e < EE) ? ei[EE + e] : (e - EE);
            atomicAdd(&hist[d >> 8], 1);
        }
    }
    __syncthreads();
    for (int t = threadIdx.x; t < BKTS; t += 256){
        int c = hist[t];
        if (c) atomicAdd(&bucketCount[t], c);
    }
}

__global__ void k_bscan(const int* __restrict__ bucketCount, int* __restrict__ bucketBase,
                        int* __restrict__ bucketCursor, int* __restrict__ rowptr){
    __shared__ int sh[512];
    int t = threadIdx.x;
    int c = (t < BKTS) ? bucketCount[t] : 0;
    sh[t] = c;
    __syncthreads();
    for (int o = 1; o < 512; o <<= 1){
        int v = (t >= o) ? sh[t - o] : 0;
        __syncthreads();
        sh[t] += v;
        __syncthreads();
    }
    if (t < BKTS){
        int excl = sh[t] - c;
        bucketBase[t] = excl;
        bucketCursor[t] = excl;
    }
    if (t == 0){
        bucketBase[BKTS] = ET;
        rowptr[NN] = ET;
    }
}

// ---------------- K3: bfill (blocks 0..219) || L0 cvt+alpha (blocks 220..610) ----
__global__ __launch_bounds__(256) void k_bfill_cvt(const int* __restrict__ ei,
        int* __restrict__ bucketCursor, unsigned* __restrict__ bpack,
        const float* __restrict__ X, f16* __restrict__ Xh,
        const float* __restrict__ Was, const float* __restrict__ Wad,
        float* __restrict__ als, float* __restrict__ ald){
    __shared__ int hist[BKTS];
    __shared__ int base[BKTS];
    if (blockIdx.x < 220){
        for (int t = threadIdx.x; t < BKTS; t += 256) hist[t] = 0;
        __syncthreads();
        const int e0 = blockIdx.x * FB_EPB + threadIdx.x;
        unsigned pk[16], rb[16];
        #pragma unroll
        for (int i = 0; i < 16; i++){
            int e = e0 + i * 256;
            rb[i] = 0xFFFFFFFFu;
            if (e < ET){
                int s, d;
                if (e < EE){ s = ei[e]; d = ei[EE + e]; } else { s = e - EE; d = s; }
                int b = d >> 8;
                int r = atomicAdd(&hist[b], 1);
                pk[i] = ((unsigned)(d & 255) << 17) | (unsigned)s;
                rb[i] = ((unsigned)r << 9) | (unsigned)b;
            }
        }
        __syncthreads();
        for (int t = threadIdx.x; t < BKTS; t += 256){
            int c = hist[t];
            base[t] = c ? atomicAdd(&bucketCursor[t], c) : 0;
        }
        __syncthreads();
        #pragma unroll
        for (int i = 0; i < 16; i++){
            if (rb[i] != 0xFFFFFFFFu){
                int b = rb[i] & 511;
                int r = rb[i] >> 9;
                bpack[base[b] + r] = pk[i];
            }
        }
        return;
    }
    // ---- L0 cvt+alpha part (stride-12 als/ald rows) ----
    int n = (blockIdx.x - 220) * 256 + threadIdx.x;
    if (n >= NN) return;
    float xr[32];
    #pragma unroll
    for (int i = 0; i < 8; i++){
        float4 v = *(const float4*)(X + (long)n * 32 + i * 4);
        xr[i * 4 + 0] = v.x; xr[i * 4 + 1] = v.y;
        xr[i * 4 + 2] = v.z; xr[i * 4 + 3] = v.w;
    }
    #pragma unroll
    for (int i = 0; i < 4; i++){
        half8 h;
        #pragma unroll
        for (int c = 0; c < 8; c++) h[c] = (f16)xr[i * 8 + c];
        *(half8*)(Xh + (long)n * 32 + i * 8) = h;
    }
    float s[10] = {}, d[10] = {};
    for (int k = 0; k < 32; k++){
        float x = xr[k];
        #pragma unroll
        for (int hd = 0; hd < 10; hd++){
            s[hd] = fmaf(x, Was[k * 10 + hd], s[hd]);
            d[hd] = fmaf(x, Wad[k * 10 + hd], d[hd]);
        }
    }
    #pragma unroll
    for (int hd = 0; hd < 10; hd++){
        als[(long)n * 12 + hd] = s[hd];
        ald[(long)n * 12 + hd] = d[hd];
    }
}

// Pass 4: block per bucket: LDS counting-sort by dstlow; coalesced rowptr+ssrc.
// Degree histogram folded in, TWO-LEVEL (round-7's per-node global atomic cost +330us).
__global__ __launch_bounds__(256) void k_bsort(const unsigned* __restrict__ bpack,
        const int* __restrict__ bucketBase, int* __restrict__ rowptr,
        int* __restrict__ ssrc, int* __restrict__ dcnt){
    __shared__ int cnt[256];
    __shared__ int off[256];
    __shared__ int dh[DBINS];
    __shared__ unsigned stage[LDSCAP];
    int b = blockIdx.x;
    int n0 = bucketBase[b], n1 = bucketBase[b + 1];
    int nE = n1 - n0;
    int t = threadIdx.x;
    cnt[t] = 0;
    if (t < DBINS) dh[t] = 0;
    __syncthreads();
    for (int i = t; i < nE; i += 256){
        unsigned v = bpack[n0 + i];
        atomicAdd(&cnt[v >> 17], 1);
    }
    __syncthreads();
    int cv = cnt[t];
    off[t] = cv;
    __syncthreads();
    for (int o = 1; o < 256; o <<= 1){
        int v = (t >= o) ? off[t - o] : 0;
        __syncthreads();
        off[t] += v;
        __syncthreads();
    }
    int excl = off[t] - cv;
    __syncthreads();
    off[t] = excl;
    cnt[t] = 0;
    __syncthreads();
    for (int i = t; i < nE; i += 256){
        unsigned v = bpack[n0 + i];
        int dl = v >> 17;
        int r = atomicAdd(&cnt[dl], 1);
        stage[off[dl] + r] = v;
    }
    int d = b * 256 + t;
    if (d < NN){
        rowptr[d] = n0 + excl;
        int dg = (cv > DBINS - 1) ? (DBINS - 1) : cv;
        atomicAdd(&dh[dg], 1);          // LDS atomic (cheap)
    }
    __syncthreads();
    for (int i = t; i < nE; i += 256){
        unsigned v = stage[i];
        ssrc[n0 + i] = (int)(v & 0x1FFFFu);
    }
    if (t < DBINS && dh[t]) atomicAdd(&dcnt[t], dh[t]);  // 64 global atomics/block
}

// ---------------- online-softmax update (proven since round 2) ----------------
__device__ __forceinline__ void smx_upd(float& ma, float& L, float& z, float e, float adv){
    float mn = fmaxf(ma, e);
    float Ln = mn + adv; Ln = (Ln >= 0.f) ? Ln : 0.2f * Ln;
    float ev = e + adv;  ev = (ev >= 0.f) ? ev : 0.2f * ev;
    z = z * __expf(L - Ln) + __expf(ev - Ln);
    ma = mn; L = Ln;
}

// ---------------- K5: L0 mzatt (blocks 1..) || degree LPT scan (block 0) ----------
// mzatt: per-(node, head-pair) online softmax -> f16 att (aggX0 consumes it).
template<int HH, int SL, int ATTS, int TPN>
__global__ __launch_bounds__(256) void k_mzatt_dscan(const float* __restrict__ als,
        const float* __restrict__ ald, const int* __restrict__ rowptr,
        const int* __restrict__ ssrc, f16* __restrict__ att,
        const int* __restrict__ dcnt, int* __restrict__ dcur){
    constexpr int HPT = HH / TPN;
    if (blockIdx.x == 0){
        // descending-degree exclusive prefix (bin 63 first -> LPT order)
        __shared__ int sh[DBINS];
        int t = threadIdx.x;
        if (t < DBINS){
            sh[t] = dcnt[t];
        }
        __syncthreads();
        if (t < DBINS){
            int off = 0;
            for (int b = t + 1; b < DBINS; ++b) off += sh[b];
            dcur[t] = off;
        }
        return;
    }
    long idx = (long)(blockIdx.x - 1) * 256 + threadIdx.x;
    if (idx >= (long)NN * TPN) return;
    int n = (int)(idx / TPN);
    int g = (int)(idx - (long)n * TPN);
    const int c0 = g * HPT;
    float adv[HPT], ma[HPT], L[HPT], z[HPT];
    #pragma unroll
    for (int h = 0; h < HPT; h++){
        adv[h] = ald[(long)n * SL + c0 + h];
        ma[h] = -1e30f; L[h] = -1e30f; z[h] = 0.f;
    }
    const int beg = rowptr[n], end = rowptr[n + 1];
    int p = beg;
    for (; p + 4 <= end; p += 4){
        int s0 = ssrc[p], s1 = ssrc[p+1], s2 = ssrc[p+2], s3 = ssrc[p+3];
        float e0[HPT], e1[HPT], e2[HPT], e3[HPT];
        if constexpr (HPT == 2){
            float2 v0 = *(const float2*)(als + (long)s0 * SL + c0);
            float2 v1 = *(const float2*)(als + (long)s1 * SL + c0);
            float2 v2 = *(const float2*)(als + (long)s2 * SL + c0);
            float2 v3 = *(const float2*)(als + (long)s3 * SL + c0);
            e0[0]=v0.x; e0[1]=v0.y; e1[0]=v1.x; e1[1]=v1.y;
            e2[0]=v2.x; e2[1]=v2.y; e3[0]=v3.x; e3[1]=v3.y;
        } else {
            e0[0] = als[(long)s0 * SL + c0];
            e1[0] = als[(long)s1 * SL + c0];
            e2[0] = als[(long)s2 * SL + c0];
            e3[0] = als[(long)s3 * SL + c0];
        }
        #pragma unroll
        for (int h = 0; h < HPT; h++){
            smx_upd(ma[h], L[h], z[h], e0[h], adv[h]);
            smx_upd(ma[h], L[h], z[h], e1[h], adv[h]);
            smx_upd(ma[h], L[h], z[h], e2[h], adv[h]);
            smx_upd(ma[h], L[h], z[h], e3[h], adv[h]);
        }
    }
    for (; p < end; ++p){
        int s = ssrc[p];
        float e[HPT];
        if constexpr (HPT == 2){
            float2 v = *(const float2*)(als + (long)s * SL + c0);
            e[0] = v.x; e[1] = v.y;
        } else {
            e[0] = als[(long)s * SL + c0];
        }
        #pragma unroll
        for (int h = 0; h < HPT; h++) smx_upd(ma[h], L[h], z[h], e[h], adv[h]);
    }
    float zi[HPT];
    int pos[HPT];
    #pragma unroll
    for (int h = 0; h < HPT; h++){
        zi[h] = 1.f / z[h];
        int hh = c0 + h;
        pos[h] = (ATTS == 16) ? (hh + ((hh >= 5) ? 3 : 0)) : hh;
    }
    for (p = beg; p < end; ++p){
        int s = ssrc[p];
        float e[HPT];
        if constexpr (HPT == 2){
            float2 v = *(const float2*)(als + (long)s * SL + c0);
            e[0] = v.x; e[1] = v.y;
        } else {
            e[0] = als[(long)s * SL + c0];
        }
        #pragma unroll
        for (int h = 0; h < HPT; h++){
            float ev = e[h] + adv[h]; ev = (ev >= 0.f) ? ev : 0.2f * ev;
            att[(long)p * ATTS + pos[h]] = (f16)(__expf(ev - L[h]) * zi[h]);
        }
    }
}

__global__ __launch_bounds__(256) void k_dfill(const int* __restrict__ rowptr,
        int* __restrict__ dcur, int* __restrict__ perm){
    __shared__ int h[DBINS];
    __shared__ int base[DBINS];
    int t = threadIdx.x;
    if (t < DBINS) h[t] = 0;
    __syncthreads();
    int n = blockIdx.x * 256 + t;
    int d = 0, r = 0;
    if (n < NN){
        d = rowptr[n + 1] - rowptr[n];
        if (d > DBINS - 1) d = DBINS - 1;
        r = atomicAdd(&h[d], 1);
    }
    __syncthreads();
    if (t < DBINS){
        int c = h[t];
        base[t] = c ? atomicAdd(&dcur[t], c) : 0;
    }
    __syncthreads();
    if (n < NN) perm[base[d] + r] = n;
}

// ---------------- L0 FUSED: aggregate X per head + block-diag MFMA GEMM + relu ----
// Nodes via degree-balanced perm (barrier waits on ~mean, not max-of-32; measured -4.4us).
__global__ __launch_bounds__(256) void k_aggX0_gemm(const f16* __restrict__ Xh,
        const f16* __restrict__ att, const int* __restrict__ rowptr,
        const int* __restrict__ ssrc, const int* __restrict__ perm,
        const f16* __restrict__ Wpk0, const float* __restrict__ bp0,
        f16* __restrict__ X1){
    constexpr int SA = 328;   // Xagg tile stride (f16)
    constexpr int SO = 264;   // X1 tile stride (f16)
    __shared__ f16 smem[32 * SA];     // 20992 B; X1 tile aliases (after barrier)
    const int t = threadIdx.x;
    const int n0 = blockIdx.x * 32;

    {   // ---- phase 1: aggregation, 4-edge unroll for MLP ----
        const int nloc = t >> 3;
        const int hg   = (t >> 2) & 1;
        const int ch   = t & 3;
        const int n    = perm[n0 + nloc];
        float acc[5][8] = {};
        int beg = rowptr[n], end = rowptr[n + 1];
        int p = beg;
        for (; p + 4 <= end; p += 4){
            int s0 = ssrc[p], s1 = ssrc[p+1], s2 = ssrc[p+2], s3 = ssrc[p+3];
            half8 x0 = *(const half8*)(Xh + (long)s0 * 32 + ch * 8);
            half8 x1 = *(const half8*)(Xh + (long)s1 * 32 + ch * 8);
            half8 x2 = *(const half8*)(Xh + (long)s2 * 32 + ch * 8);
            half8 x3 = *(const half8*)(Xh + (long)s3 * 32 + ch * 8);
            half8 a0 = *(const half8*)(att + (long)p * 16 + hg * 8);
            half8 a1 = *(const half8*)(att + (long)(p+1) * 16 + hg * 8);
            half8 a2 = *(const half8*)(att + (long)(p+2) * 16 + hg * 8);
            half8 a3 = *(const half8*)(att + (long)(p+3) * 16 + hg * 8);
            #pragma unroll
            for (int h = 0; h < 5; h++){
                float w0 = (float)a0[h], w1 = (float)a1[h];
                float w2 = (float)a2[h], w3 = (float)a3[h];
                #pragma unroll
                for (int c = 0; c < 8; c++){
                    acc[h][c] = fmaf(w0, (float)x0[c], acc[h][c]);
                    acc[h][c] = fmaf(w1, (float)x1[c], acc[h][c]);
                    acc[h][c] = fmaf(w2, (float)x2[c], acc[h][c]);
                    acc[h][c] = fmaf(w3, (float)x3[c], acc[h][c]);
                }
            }
        }
        for (; p < end; ++p){
            int s = ssrc[p];
            half8 xv = *(const half8*)(Xh + (long)s * 32 + ch * 8);
            half8 av = *(const half8*)(att + (long)p * 16 + hg * 8);
            #pragma unroll
            for (int h = 0; h < 5; h++){
                float w = (float)av[h];
                #pragma unroll
                for (int c = 0; c < 8; c++)
                    acc[h][c] = fmaf(w, (float)xv[c], acc[h][c]);
            }
        }
        #pragma unroll
        for (int h = 0; h < 5; h++){
            half8 o;
            #pragma unroll
            for (int c = 0; c < 8; c++) o[c] = (f16)acc[h][c];
            *(half8*)(smem + nloc * SA + (hg * 5 + h) * 32 + ch * 8) = o;
        }
    }
    __syncthreads();

    // ---- phase 2: prefetch A-frags, then MFMA + epilogue into LDS X1 tile ----
    const int wave = t >> 6;
    const int lane = t & 63;
    const int quad = lane >> 4;
    const int l16  = lane & 15;
    const int mt   = wave & 1;
    half8 afr[5];
    #pragma unroll
    for (int i = 0; i < 5; i++){
        const int hd = (wave + 4 * i) >> 1;
        afr[i] = *(const half8*)(smem + (mt * 16 + l16) * SA + hd * 32 + quad * 8);
    }
    __syncthreads();                    // all Xagg reads done before overwrite
    #pragma unroll
    for (int i = 0; i < 5; i++){
        const int hd = (wave + 4 * i) >> 1;
        #pragma unroll
        for (int nt = 0; nt < 2; nt++){
            half8 bfr = *(const half8*)(Wpk0 + ((hd * 2 + nt) * 64 + lane) * 8);
            f32x4 acc2 = (f32x4){0.f, 0.f, 0.f, 0.f};
            acc2 = __builtin_amdgcn_mfma_f32_16x16x32_f16(afr[i], bfr, acc2, 0, 0, 0);
            int cih = nt * 16 + l16;
            if (cih < 24){
                float bv = bp0[hd * 24 + cih];
                #pragma unroll
                for (int reg = 0; reg < 4; reg++){
                    int rl = mt * 16 + quad * 4 + reg;
                    float v = acc2[reg] + bv;
                    smem[rl * SO + hd * 24 + cih] = (f16)((v > 0.f) ? v : 0.f);
                }
            }
        }
    }
    __syncthreads();

    // ---- phase 3: coalesced X1 stores (rows scattered via perm, 512B each) ----
    const half8 hz = {};
    #pragma unroll
    for (int c = t; c < 1024; c += 256){
        int row = c >> 5, c8 = c & 31;
        long rn = perm[n0 + row];
        half8 v = (c8 >= 30) ? hz : *(const half8*)(smem + row * SO + c8 * 8);
        *(half8*)(X1 + rn * 256 + c8 * 8) = v;
    }
}

// ---------------- MFMA GEMM + fused alpha (layers 1..4) ----------------
// GEMM writes the 128-row H tile to global AND to LDS; after a barrier the block
// computes als/ald from the LDS tile (saves the alpha dispatch + H2 re-read).
template<int KP, int MPH, int M, int HH, int CC, int SL>
__global__ __launch_bounds__(256) void k_gemm_alpha(const f16* __restrict__ Xh,
        const f16* __restrict__ Wpk, const float* __restrict__ as_,
        const float* __restrict__ ad_, f16* __restrict__ H2,
        float* __restrict__ als, float* __restrict__ ald){
    constexpr int NT = MPH / 16;
    constexpr int KS = KP / 32;
    __shared__ f16 hs[128 * MPH];      // 32KB @ MPH=128
    const int wave = threadIdx.x >> 6;
    const int lane = threadIdx.x & 63;
    const int quad = lane >> 4;
    const int l16  = lane & 15;
    const long row0 = (long)blockIdx.x * 128 + wave * 32;

    f32x4 acc[2][NT];
    #pragma unroll
    for (int mt = 0; mt < 2; mt++)
        #pragma unroll
        for (int nt = 0; nt < NT; nt++)
            acc[mt][nt] = (f32x4){0.f, 0.f, 0.f, 0.f};

    const long r0 = row0 + l16;
    const long r1 = row0 + 16 + l16;
    const half8 hz = {};
    half8 a0 = (r0 < NN) ? *(const half8*)(Xh + r0 * KP + quad * 8) : hz;
    half8 a1 = (r1 < NN) ? *(const half8*)(Xh + r1 * KP + quad * 8) : hz;
    half8 bc[NT];
    #pragma unroll
    for (int nt = 0; nt < NT; nt++)
        bc[nt] = *(const half8*)(Wpk + ((long)nt * 64 + lane) * 8);

    for (int ks = 0; ks < KS; ks++){
        half8 n0 = hz, n1 = hz, bn[NT];
        if (ks + 1 < KS){
            const int kk = (ks + 1) * 32 + quad * 8;
            n0 = (r0 < NN) ? *(const half8*)(Xh + r0 * KP + kk) : hz;
            n1 = (r1 < NN) ? *(const half8*)(Xh + r1 * KP + kk) : hz;
            const f16* bp_ = Wpk + ((long)(ks + 1) * NT * 64 + lane) * 8;
            #pragma unroll
            for (int nt = 0; nt < NT; nt++)
                bn[nt] = *(const half8*)(bp_ + (long)nt * 512);
        } else {
            #pragma unroll
            for (int nt = 0; nt < NT; nt++) bn[nt] = hz;
        }
        #pragma unroll
        for (int nt = 0; nt < NT; nt++){
            acc[0][nt] = __builtin_amdgcn_mfma_f32_16x16x32_f16(a0, bc[nt], acc[0][nt], 0, 0, 0);
            acc[1][nt] = __builtin_amdgcn_mfma_f32_16x16x32_f16(a1, bc[nt], acc[1][nt], 0, 0, 0);
        }
        a0 = n0; a1 = n1;
        #pragma unroll
        for (int nt = 0; nt < NT; nt++) bc[nt] = bn[nt];
    }
    #pragma unroll
    for (int mt = 0; mt < 2; mt++){
        #pragma unroll
        for (int reg = 0; reg < 4; reg++){
            const int rl = wave * 32 + mt * 16 + quad * 4 + reg;
            long r = row0 + mt * 16 + quad * 4 + reg;
            #pragma unroll
            for (int nt = 0; nt < NT; nt++)
                hs[rl * MPH + nt * 16 + l16] = (f16)acc[mt][nt][reg];
            if (r < NN){
                #pragma unroll
                for (int nt = 0; nt < NT; nt++)
                    H2[r * MPH + nt * 16 + l16] = (f16)acc[mt][nt][reg];
            }
        }
    }
    __syncthreads();

    // ---- fused alpha: per (row, head) dot with as/ad from the LDS tile ----
    const long nb = (long)blockIdx.x * 128;
    for (int tk = threadIdx.x; tk < 128 * HH; tk += 256){
        int row = tk / HH, hd = tk - row * HH;
        long n = nb + row;
        if (n < NN){
            const f16* hrow = hs + row * MPH + hd * CC;
            float s = 0.f, d = 0.f;
            #pragma unroll
            for (int c0 = 0; c0 < CC; c0 += 4){
                half4 hv = *(const half4*)(hrow + c0);
                #pragma unroll
                for (int j = 0; j < 4; j++){
                    float w = (float)hv[j];
                    s = fmaf(w, as_[hd * CC + c0 + j], s);
                    d = fmaf(w, ad_[hd * CC + c0 + j], d);
                }
            }
            als[n * SL + hd] = s;
            ald[n * SL + hd] = d;
        }
    }
}

// ---------------- col-chunk fused softmax+aggregate (layers 1..4; round-8 form) ----
template<int HH, int CC, int MPH, int MPO, int VEC, bool O16, int SL>
__global__ __launch_bounds__(256) void k_aggsm_h(const f16* __restrict__ H2,
        const float* __restrict__ als, const float* __restrict__ ald,
        const int* __restrict__ rowptr, const int* __restrict__ ssrc,
        const float* __restrict__ bp, f16* __restrict__ out16,
        float* __restrict__ out32, int MREAL){
    constexpr int TPN = MPO / VEC;
    typedef typename HV<VEC>::type hvec;
    long idx = (long)blockIdx.x * 256 + threadIdx.x;
    if (idx >= (long)NN * TPN) return;
    int n = (int)(idx / TPN);
    int q = (int)(idx - (long)n * TPN);
    int j0 = q * VEC;
    if constexpr (!O16){ if (j0 >= MREAL) return; }
    int hd = j0 / CC; if (hd > HH - 1) hd = HH - 1;
    const float adv = ald[(long)n * SL + hd];
    const int beg = rowptr[n], end = rowptr[n + 1];

    float ma = -1e30f, L = -1e30f, z = 0.f;
    int p = beg;
    for (; p + 4 <= end; p += 4){
        int s0 = ssrc[p], s1 = ssrc[p+1], s2 = ssrc[p+2], s3 = ssrc[p+3];
        float e0 = als[(long)s0 * SL + hd];
        float e1 = als[(long)s1 * SL + hd];
        float e2 = als[(long)s2 * SL + hd];
        float e3 = als[(long)s3 * SL + hd];
        smx_upd(ma, L, z, e0, adv);
        smx_upd(ma, L, z, e1, adv);
        smx_upd(ma, L, z, e2, adv);
        smx_upd(ma, L, z, e3, adv);
    }
    for (; p < end; ++p)
        smx_upd(ma, L, z, als[(long)ssrc[p] * SL + hd], adv);
    const float zi = 1.f / z;

    float acc[VEC] = {};
    p = beg;
    for (; p + 4 <= end; p += 4){
        int s0 = ssrc[p], s1 = ssrc[p+1], s2 = ssrc[p+2], s3 = ssrc[p+3];
        float e0 = als[(long)s0 * SL + hd];
        float e1 = als[(long)s1 * SL + hd];
        float e2 = als[(long)s2 * SL + hd];
        float e3 = als[(long)s3 * SL + hd];
        e0 += adv; e0 = (e0 >= 0.f) ? e0 : 0.2f * e0;
        e1 += adv; e1 = (e1 >= 0.f) ? e1 : 0.2f * e1;
        e2 += adv; e2 = (e2 >= 0.f) ? e2 : 0.2f * e2;
        e3 += adv; e3 = (e3 >= 0.f) ? e3 : 0.2f * e3;
        float w0 = __expf(e0 - L) * zi;
        float w1 = __expf(e1 - L) * zi;
        float w2 = __expf(e2 - L) * zi;
        float w3 = __expf(e3 - L) * zi;
        hvec h0 = *(const hvec*)(H2 + (long)s0 * MPH + j0);
        hvec h1 = *(const hvec*)(H2 + (long)s1 * MPH + j0);
        hvec h2 = *(const hvec*)(H2 + (long)s2 * MPH + j0);
        hvec h3 = *(const hvec*)(H2 + (long)s3 * MPH + j0);
        #pragma unroll
        for (int c = 0; c < VEC; c++){
            acc[c] = fmaf(w0, (float)h0[c], acc[c]);
            acc[c] = fmaf(w1, (float)h1[c], acc[c]);
            acc[c] = fmaf(w2, (float)h2[c], acc[c]);
            acc[c] = fmaf(w3, (float)h3[c], acc[c]);
        }
    }
    for (; p < end; ++p){
        int s = ssrc[p];
        float e = als[(long)s * SL + hd] + adv;
        e = (e >= 0.f) ? e : 0.2f * e;
        float w = __expf(e - L) * zi;
        hvec hv = *(const hvec*)(H2 + (long)s * MPH + j0);
        #pragma unroll
        for (int c = 0; c < VEC; c++)
            acc[c] = fmaf(w, (float)hv[c], acc[c]);
    }
    if constexpr (O16){
        hvec o;
        #pragma unroll
        for (int c = 0; c < VEC; c++){
            float v = acc[c] + bp[j0 + c];
            o[c] = (f16)((v > 0.f) ? v : 0.f);
        }
        *(hvec*)(out16 + (long)n * MPO + j0) = o;
    } else {
        #pragma unroll
        for (int c = 0; c < VEC; c++){
            float v = acc[c] + bp[j0 + c];
            out32[(long)n * MREAL + j0 + c] = (v > 0.f) ? v : 0.f;
        }
    }
}

// ---------------- layer driver (layers 1..4): 2 dispatches/layer ----------------
template<int K, int M, int KP, int MPH, int MPO, int HH, int CC, int VEC, bool O16, int SL>
static void run_layer(const f16* Xin, f16* H2,
                      const f16* Wpk, const float* bp,
                      const float* asv, const float* adv,
                      float* als, float* ald,
                      const int* rowptr, const int* ssrc,
                      f16* Xnext, float* out32, hipStream_t stream){
    constexpr int OTPN = MPO / VEC;
    k_gemm_alpha<KP, MPH, M, HH, CC, SL><<<cdiv(NN, 128), 256, 0, stream>>>(
        Xin, Wpk, asv, adv, H2, als, ald);
    k_aggsm_h<HH, CC, MPH, MPO, VEC, O16, SL><<<cdiv((long)NN * OTPN, 256), 256, 0, stream>>>(
        H2, als, ald, rowptr, ssrc, bp, Xnext, out32, M);
}

extern "C" void kernel_launch(void* const* d_in, const int* in_sizes, int n_in,
                              void* d_out, int out_size, void* d_ws, size_t ws_size,
                              hipStream_t stream){
    const float* x0 = (const float*)d_in[0];
    const int*   ei = (const int*)d_in[1];
    PrepAll pa;
    for (int i = 0; i < 5; i++){
        pa.W[i]  = (const float*)d_in[3 + 4 * i];
        pa.b[i]  = (const float*)d_in[4 + 4 * i];
        pa.as[i] = (const float*)d_in[5 + 4 * i];
        pa.ad[i] = (const float*)d_in[6 + 4 * i];
    }

    char* p = (char*)d_ws;
    auto alloc = [&](size_t bytes) -> char* {
        char* r = p;
        p += (bytes + 255) & ~(size_t)255;
        return r;
    };
    f16*   Xh     = (f16*)alloc((size_t)NN * 256 * 2);   // X0h (stride 32), then hidden H (layers 1..4)
    f16*   H2     = (f16*)alloc((size_t)NN * 320 * 2);   // X1 (stride 256), then X2/X3/X4 activations
    f16*   att    = (f16*)alloc((size_t)ET * 16 * 2);    // L0 only
    float* als    = (float*)alloc((size_t)NN * 12 * 4);  // padded rows (stride 12/8/2/1/1)
    float* ald    = (float*)alloc((size_t)NN * 12 * 4);
    const int wpkSz[5] = {7680, 32768, 8192, 2048, 512};
    const int mpSz[5]  = {240, 128, 64, 32, 16};
    const int khSz[5]  = {320, 1200, 240, 48, 24};
    for (int i = 0; i < 5; i++){
        pa.Wpk[i] = (f16*)alloc((size_t)wpkSz[i] * 2);
        pa.bp[i]  = (float*)alloc((size_t)mpSz[i] * 4);
        pa.Was[i] = (float*)alloc((size_t)khSz[i] * 4);
        pa.Wad[i] = (float*)alloc((size_t)khSz[i] * 4);
    }
    pa.Wpk0 = (f16*)alloc((size_t)10240 * 2);
    int*      cntbuf       = (int*)alloc((size_t)(BKTS + DBINS) * 4);
    int*      bucketCount  = cntbuf;            // zeroed by one memset
    int*      dcnt         = cntbuf + BKTS;
    int*      bucketBase   = (int*)alloc((size_t)(BKTS + 1) * 4);
    int*      bucketCursor = (int*)alloc((size_t)BKTS * 4);
    unsigned* bpack        = (unsigned*)alloc((size_t)ET * 4);
    int*      rowptr       = (int*)alloc((size_t)(NN + 1) * 4);
    int*      ssrc         = (int*)alloc((size_t)ET * 4);
    int*      dcur         = (int*)alloc((size_t)DBINS * 4);
    int*      perm         = (int*)alloc((size_t)NN * 4);

    // ---- zero counters (stream-ordered, graph-capture safe) ----
    hipMemsetAsync(cntbuf, 0, (size_t)(BKTS + DBINS) * 4, stream);

    // ---- K1: prep || bhist;  K2: bscan;  K3: bfill || L0 cvt+alpha;
    //      K4: bsort (+deg hist);  K5: L0 mzatt || dscan;  K6: dfill ----
    k_prep_bhist<<<240 + cdiv(ET, FB_EPB), 256, 0, stream>>>(pa, ei, bucketCount);
    k_bscan<<<1, 512, 0, stream>>>(bucketCount, bucketBase, bucketCursor, rowptr);
    k_bfill_cvt<<<cdiv(ET, FB_EPB) + cdiv(NN, 256), 256, 0, stream>>>(
        ei, bucketCursor, bpack, x0, Xh, pa.Was[0], pa.Wad[0], als, ald);
    k_bsort<<<BKTS, 256, 0, stream>>>(bpack, bucketBase, rowptr, ssrc, dcnt);
    k_mzatt_dscan<10, 12, 16, 5><<<1 + cdiv((long)NN * 5, 256), 256, 0, stream>>>(
        als, ald, rowptr, ssrc, att, dcnt, dcur);
    k_dfill<<<cdiv(NN, 256), 256, 0, stream>>>(rowptr, dcur, perm);

    // ---- L0 fused agg+GEMM (Xagg never hits HBM) ----
    k_aggX0_gemm<<<NN / 32, 256, 0, stream>>>(Xh, att, rowptr, ssrc, perm,
        pa.Wpk0, pa.bp[0], H2 /*X1, stride 256*/);

    // ---- Layers 1..4 (2 dispatches each; alpha fused into GEMM epilogue) ----
    //         K    M   KP  MPH  MPO  HH  CC VEC  O16  SL
    run_layer<240, 120, 256, 128, 128,  5, 24, 8, true,  8>(H2, Xh, pa.Wpk[1],
        pa.bp[1], pa.as[1], pa.ad[1], als, ald, rowptr, ssrc, H2, nullptr, stream);
    run_layer<120,  48, 128,  64,  64,  2, 24, 8, true,  2>(H2, Xh, pa.Wpk[2],
        pa.bp[2], pa.as[2], pa.ad[2], als, ald, rowptr, ssrc, H2, nullptr, stream);
    run_layer< 48,  24,  64,  32,  32,  1, 24, 8, true,  1>(H2, Xh, pa.Wpk[3],
        pa.bp[3], pa.as[3], pa.ad[3], als, ald, rowptr, ssrc, H2, nullptr, stream);
    run_layer< 24,  12,  32,  16,  16,  1, 12, 4, false, 1>(H2, Xh, pa.Wpk[4],
        pa.bp[4], pa.as[4], pa.ad[4], als, ald, rowptr, ssrc, nullptr, (float*)d_out, stream);
}